// Round 17
// baseline (2007.884 us; speedup 1.0000x reference)
//
#include <hip/hip_runtime.h>

#define BATCHN 128
#define SEQT   2048
#define FEAT   64
#define UNITS  64
#define NCOL   256   // 4*UNITS gate columns
#define OUTD   6
#define NTICK  1030  // 1024 active + 5 skew + 1 pad (even for 2-unroll)

typedef __fp16 hv2 __attribute__((ext_vector_type(2)));

__device__ __forceinline__ float fast_exp2(float x) {
#if __has_builtin(__builtin_amdgcn_exp2f)
    return __builtin_amdgcn_exp2f(x);
#else
    return exp2f(x);
#endif
}
__device__ __forceinline__ float fast_rcp(float x) {
#if __has_builtin(__builtin_amdgcn_rcpf)
    return __builtin_amdgcn_rcpf(x);
#else
    return 1.0f / x;
#endif
}
__device__ __forceinline__ float sig_(float x) {
    return fast_rcp(1.0f + fast_exp2(-1.4426950408889634f * x));
}
// tanh(x) = 2/(1+e^{-2x}) - 1
__device__ __forceinline__ float tanh_(float x) {
    float e = fast_exp2(-2.8853900817779268f * x);   // e^{-2x}
    return fmaf(2.0f, fast_rcp(1.0f + e), -1.0f);
}

// 2xf16 MAC with f32 accumulate (v_dot2_f32_f16)
__device__ __forceinline__ float fdot2_(hv2 a, hv2 b, float c) {
#if __has_builtin(__builtin_amdgcn_fdot2)
    return __builtin_amdgcn_fdot2(a, b, c, false);
#else
    return fmaf((float)a.x, (float)b.x, fmaf((float)a.y, (float)b.y, c));
#endif
}
__device__ __forceinline__ hv2 cvtpk_(float a, float b) {
    return __builtin_amdgcn_cvt_pkrtz(a, b);
}
// wave-uniform broadcast of lane l's u32 (compile-time l)
__device__ __forceinline__ unsigned int rlane_(unsigned int v, int l) {
    return (unsigned int)__builtin_amdgcn_readlane((int)v, l);
}
// wave-uniform broadcast of lane l's f32
__device__ __forceinline__ float rlf_(float v, int l) {
    return __builtin_bit_cast(float,
        __builtin_amdgcn_readlane(__builtin_bit_cast(int, v), l));
}
// pull f32 from lane (byteaddr/4)
__device__ __forceinline__ float bperm_(int byteaddr, float v) {
    return __builtin_bit_cast(float,
        __builtin_amdgcn_ds_bpermute(byteaddr, __builtin_bit_cast(int, v)));
}
__device__ __forceinline__ unsigned int pku_(hv2 v) {
    return __builtin_bit_cast(unsigned int, v);
}

// 6 waves = (layer g, role r); FF holds W, REC holds U (128 f16-pair VGPRs).
// TWO timesteps per barrier tick: REC chains step t1 off step t0's h via
// in-register readlane+cvtpk (no LDS hop). Skew alpha=2g+r in tick units;
// wave at tick T processes steps 2(T-alpha), 2(T-alpha)+1. All cross-wave
// handoffs are previous-tick. Barrier count halves vs R16: 2054 -> 1030.
__global__ __launch_bounds__(384, 1)
void lstm3_2step(const float* __restrict__ x,
                 const float* __restrict__ W0, const float* __restrict__ U0,
                 const float* __restrict__ b0,
                 const float* __restrict__ W1, const float* __restrict__ U1,
                 const float* __restrict__ b1,
                 const float* __restrict__ Wf, const float* __restrict__ bfv,
                 const float* __restrict__ Wo, const float* __restrict__ bov,
                 float* __restrict__ out)
{
    const int b   = blockIdx.x;
    const int tid = threadIdx.x;   // 0..383
    const int wid = tid >> 6;      // 0..5
    const int g   = wid >> 1;      // layer 0,1,2
    const int r   = wid & 1;       // 0=FF (W), 1=REC (U + activations)
    const int u   = tid & 63;      // unit/lane
    const int j32 = u & 31;

    __shared__ unsigned int lhp[3][2][2][32];               // h pairs [g][tickpar][slot]
    __shared__ __align__(16) float lzf[3][2][2][UNITS][4];  // z_ff [g][tickpar][slot]
    __shared__ float lh2f[UNITS];
    __shared__ float lact[UNITS];

    // ---- weights: 4 cols x 64 k of ONE matrix, f16 k-pairs (128 VGPRs) ----
    const float* M = (g == 0) ? ((r == 0) ? W0 : U0) : ((r == 0) ? W1 : U1);
    const float* bsel = (g == 0) ? b0 : b1;

    hv2 wM[32][4];
    float biasv[4];
#pragma unroll
    for (int gg = 0; gg < 4; ++gg) {
        const int col = (gg << 6) + u;
#pragma unroll
        for (int j = 0; j < 32; ++j) {
            hv2 w;
            w.x = (__fp16)M[(2 * j) * NCOL + col];
            w.y = (__fp16)M[(2 * j + 1) * NCOL + col];
            wM[j][gg] = w;
        }
        biasv[gg] = bsel[col];   // only FF adds it
    }

    // zero handoff buffers (cosmetic; real data arrives before first use)
    if (tid < 384) ((unsigned int*)lhp)[tid] = 0u;
    for (int i = tid; i < 3 * 2 * 2 * UNITS * 4; i += 384) ((float*)lzf)[i] = 0.f;

    // x: wave 0 (FF_0), lanes<32 hold pairs (x[t][2u], x[t][2u+1]); 2 steps/tick,
    // prefetched 2 ticks (4 steps) ahead in named regs
    const float2* x2 = (const float2*)(x + (size_t)b * SEQT * FEAT);
    float2 xA0 = {0.f,0.f}, xA1 = {0.f,0.f}, xB0 = {0.f,0.f}, xB1 = {0.f,0.f};
    if (wid == 0 && u < 32) {
        xA0 = x2[0 * 32 + u];  xA1 = x2[1 * 32 + u];   // tick 0: steps 0,1
        xB0 = x2[2 * 32 + u];  xB1 = x2[3 * 32 + u];   // tick 1: steps 2,3
    }
    __syncthreads();

    const int alpha = 2 * g + r;
    float c = 0.f;
    unsigned int rpk = 0u;       // REC: own h(t-1) packed (lane j<32 = pair j)

    // dot over packed-pair source broadcast by readlane
#define DOT_PK(SRC, S0, S1, S2, S3)                                           \
    {                                                                         \
        float dA0=0.f,dA1=0.f,dA2=0.f,dA3=0.f,dB0=0.f,dB1=0.f,dB2=0.f,dB3=0.f;\
        _Pragma("unroll")                                                     \
        for (int j = 0; j < 32; j += 2) {                                     \
            hv2 p0 = __builtin_bit_cast(hv2, rlane_(SRC, j));                 \
            hv2 p1 = __builtin_bit_cast(hv2, rlane_(SRC, j + 1));             \
            dA0 = fdot2_(p0, wM[j][0], dA0);                                  \
            dA1 = fdot2_(p0, wM[j][1], dA1);                                  \
            dA2 = fdot2_(p0, wM[j][2], dA2);                                  \
            dA3 = fdot2_(p0, wM[j][3], dA3);                                  \
            dB0 = fdot2_(p1, wM[j + 1][0], dB0);                              \
            dB1 = fdot2_(p1, wM[j + 1][1], dB1);                              \
            dB2 = fdot2_(p1, wM[j + 1][2], dB2);                              \
            dB3 = fdot2_(p1, wM[j + 1][3], dB3);                              \
        }                                                                     \
        S0 = dA0 + dB0; S1 = dA1 + dB1; S2 = dA2 + dB2; S3 = dA3 + dB3;       \
    }

    // dot over f32 h source: pairs built by readlane+cvtpk (12-cyc hops, no bperm)
#define DOT_H(HV, S0, S1, S2, S3)                                             \
    {                                                                         \
        float dA0=0.f,dA1=0.f,dA2=0.f,dA3=0.f,dB0=0.f,dB1=0.f,dB2=0.f,dB3=0.f;\
        _Pragma("unroll")                                                     \
        for (int j = 0; j < 32; j += 2) {                                     \
            hv2 p0 = cvtpk_(rlf_(HV, 2 * j),     rlf_(HV, 2 * j + 1));        \
            hv2 p1 = cvtpk_(rlf_(HV, 2 * j + 2), rlf_(HV, 2 * j + 3));        \
            dA0 = fdot2_(p0, wM[j][0], dA0);                                  \
            dA1 = fdot2_(p0, wM[j][1], dA1);                                  \
            dA2 = fdot2_(p0, wM[j][2], dA2);                                  \
            dA3 = fdot2_(p0, wM[j][3], dA3);                                  \
            dB0 = fdot2_(p1, wM[j + 1][0], dB0);                              \
            dB1 = fdot2_(p1, wM[j + 1][1], dB1);                              \
            dB2 = fdot2_(p1, wM[j + 1][2], dB2);                              \
            dB3 = fdot2_(p1, wM[j + 1][3], dB3);                              \
        }                                                                     \
        S0 = dA0 + dB0; S1 = dA1 + dB1; S2 = dA2 + dB2; S3 = dA3 + dB3;       \
    }

#define GATES(Z0, Z1, Z2, Z3, HOUT)                                           \
    {                                                                         \
        const float ig = sig_(Z0), fg = sig_(Z1);                             \
        const float gv = tanh_(Z2), og = sig_(Z3);                            \
        c = fg * c + ig * gv;                                                 \
        HOUT = og * tanh_(c);                                                 \
    }

#define TICK(TK, X0, X1)                                                      \
    {                                                                         \
        const int t0_ = 2 * ((TK) - alpha);                                   \
        const float2 xc0 = X0, xc1 = X1;                                      \
        if (wid == 0 && u < 32) {    /* refill with tick (TK)+2's steps */    \
            int tn = 2 * ((TK) + 2);                                          \
            if (tn > SEQT - 2) tn = SEQT - 2;                                 \
            X0 = x2[(size_t)tn * 32 + u];                                     \
            X1 = x2[(size_t)(tn + 1) * 32 + u];                               \
        }                                                                     \
        if (t0_ >= 0 && t0_ < SEQT) {                                         \
            const int q_ = (TK) & 1;                                          \
            if (r == 0) {                                                     \
                unsigned int fp0, fp1;                                        \
                if (g == 0) {                                                 \
                    fp0 = pku_(cvtpk_(xc0.x, xc0.y));                         \
                    fp1 = pku_(cvtpk_(xc1.x, xc1.y));                         \
                } else {                                                      \
                    fp0 = lhp[g - 1][q_ ^ 1][0][j32];                         \
                    fp1 = lhp[g - 1][q_ ^ 1][1][j32];                         \
                }                                                             \
                float s0, s1, s2, s3;                                         \
                DOT_PK(fp0, s0, s1, s2, s3)                                   \
                {                                                             \
                    float4 z4 = {s0 + biasv[0], s1 + biasv[1],                \
                                 s2 + biasv[2], s3 + biasv[3]};               \
                    *(float4*)&lzf[g][q_][0][u][0] = z4;                      \
                }                                                             \
                DOT_PK(fp1, s0, s1, s2, s3)                                   \
                {                                                             \
                    float4 z4 = {s0 + biasv[0], s1 + biasv[1],                \
                                 s2 + biasv[2], s3 + biasv[3]};               \
                    *(float4*)&lzf[g][q_][1][u][0] = z4;                      \
                }                                                             \
            } else {                                                          \
                float4 zin0 = *(const float4*)&lzf[g][q_ ^ 1][0][u][0];       \
                float4 zin1 = *(const float4*)&lzf[g][q_ ^ 1][1][u][0];       \
                float s0, s1, s2, s3, h0v, h1v;                               \
                DOT_PK(rpk, s0, s1, s2, s3)                                   \
                GATES(s0 + zin0.x, s1 + zin0.y, s2 + zin0.z, s3 + zin0.w, h0v)\
                DOT_H(h0v, s0, s1, s2, s3)                                    \
                GATES(s0 + zin1.x, s1 + zin1.y, s2 + zin1.z, s3 + zin1.w, h1v)\
                {   /* publish both slots; rpk <- packed h1 for next tick */  \
                    const float pa = bperm_(j32 * 8,     h0v);                \
                    const float pb = bperm_(j32 * 8 + 4, h0v);                \
                    const unsigned int pk0 = pku_(cvtpk_(pa, pb));            \
                    const float pc = bperm_(j32 * 8,     h1v);                \
                    const float pd = bperm_(j32 * 8 + 4, h1v);                \
                    rpk = pku_(cvtpk_(pc, pd));                               \
                    if (u < 32) {                                             \
                        lhp[g][q_][0][u] = pk0;                               \
                        lhp[g][q_][1][u] = rpk;                               \
                    }                                                         \
                }                                                             \
                if (g == 2 && t0_ == SEQT - 2) lh2f[u] = h1v;                 \
            }                                                                 \
        }                                                                     \
        asm volatile("s_waitcnt lgkmcnt(0)\n\ts_barrier" ::: "memory");       \
    }

    for (int tk = 0; tk < NTICK; tk += 2) {
        TICK(tk,     xA0, xA1)
        TICK(tk + 1, xB0, xB1)
    }
#undef TICK
#undef GATES
#undef DOT_H
#undef DOT_PK

    __syncthreads();

    // ---- dense head on final h2 (f32) ----
    if (tid < UNITS) {
        float a = bfv[tid];
#pragma unroll
        for (int k = 0; k < UNITS; ++k) a += lh2f[k] * Wf[k * 64 + tid];
        lact[tid] = fmaxf(a, 0.f);
    }
    __syncthreads();
    if (tid < OUTD) {
        float a = bov[tid];
#pragma unroll
        for (int k = 0; k < UNITS; ++k) a += lact[k] * Wo[k * OUTD + tid];
        out[b * OUTD + tid] = a;
    }
}

extern "C" void kernel_launch(void* const* d_in, const int* in_sizes, int n_in,
                              void* d_out, int out_size, void* d_ws, size_t ws_size,
                              hipStream_t stream) {
    const float* x   = (const float*)d_in[0];
    const float* W0  = (const float*)d_in[1];
    const float* U0  = (const float*)d_in[2];
    const float* b0  = (const float*)d_in[3];
    const float* W1  = (const float*)d_in[4];
    const float* U1  = (const float*)d_in[5];
    const float* b1  = (const float*)d_in[6];
    const float* Wf  = (const float*)d_in[7];
    const float* bfv = (const float*)d_in[8];
    const float* Wo  = (const float*)d_in[9];
    const float* bov = (const float*)d_in[10];
    float* out = (float*)d_out;

    lstm3_2step<<<BATCHN, 384, 0, stream>>>(x, W0, U0, b0, W1, U1, b1,
                                            Wf, bfv, Wo, bov, out);
}